// Round 18
// baseline (211.182 us; speedup 1.0000x reference)
//
#include <hip/hip_runtime.h>
#include <hip/hip_bf16.h>

#define D_MODEL 1024
#define NHEADS  16
#define HD      64
#define BATCH   4
#define SEQ     2048
#define MROWS   (BATCH*SEQ)   // 8192
#define NKV     (SEQ/64)      // 32 kv-tiles per bh
#define NKV2    (NKV/2)       // 16 tiles per half
#define BHROWS  (BATCH*NHEADS*SEQ)   // 131072

typedef __attribute__((ext_vector_type(8))) short bf16x8;
typedef __attribute__((ext_vector_type(4))) float f32x4;
typedef __attribute__((ext_vector_type(16))) float f32x16;
typedef __attribute__((ext_vector_type(2))) float f32x2;
typedef __attribute__((ext_vector_type(4))) unsigned int u32x4;
typedef __attribute__((ext_vector_type(2))) unsigned int u32x2;
#define MFMA16(a,b,c) __builtin_amdgcn_mfma_f32_16x16x32_bf16(a,b,c,0,0,0)
#define MFMA32(a,b,c) __builtin_amdgcn_mfma_f32_32x32x16_bf16(a,b,c,0,0,0)

__device__ __forceinline__ short f2bf(float f) {
    __hip_bfloat16 h = __float2bfloat16(f);   // RNE
    return *reinterpret_cast<short*>(&h);
}
__device__ __forceinline__ float bf2f(short s) {
    __hip_bfloat16 h = *reinterpret_cast<__hip_bfloat16*>(&s);
    return __bfloat162float(h);
}
// single-instruction packed f32x2 -> bf16x2 (T12; RNE)
__device__ __forceinline__ unsigned cvtpk(float a, float b) {
    unsigned r; asm("v_cvt_pk_bf16_f32 %0, %1, %2" : "=v"(r) : "v"(a), "v"(b)); return r;
}
// raw 2^x (v_exp_f32 is natively exp2)
__device__ __forceinline__ float fexp2(float x) {
    float r; asm("v_exp_f32 %0, %1" : "=v"(r) : "v"(x)); return r;
}
// full-rate packed fp32 add (CDNA dual-f32 pipe)
__device__ __forceinline__ f32x2 pkadd(f32x2 a, f32x2 b) {
    f32x2 d; asm("v_pk_add_f32 %0, %1, %2" : "=v"(d) : "v"(a), "v"(b)); return d;
}
#define SH2(V,I) __builtin_shufflevector(V, V, I, (I)+1)

typedef const __attribute__((address_space(1))) unsigned char* gas_t;
typedef __attribute__((address_space(3))) unsigned char* las_t;
#define GLD16(gp, lp) __builtin_amdgcn_global_load_lds((gas_t)(gp), (las_t)(lp), 16, 0, 0)

// ---------------- fused prep: round x to bf16 + 4x W transpose ----------------
__global__ __launch_bounds__(256) void prep(
    const float* __restrict__ x,
    const float* __restrict__ Wq, const float* __restrict__ Wk,
    const float* __restrict__ Wv, const float* __restrict__ Wo,
    short* __restrict__ xb,
    short* __restrict__ WqT, short* __restrict__ WkT,
    short* __restrict__ WvT, short* __restrict__ WoT)
{
    __shared__ float tile[64][65];
    const int bid = blockIdx.x;
    const int t = threadIdx.x;
    if (bid < 4096) {
        const size_t i = ((size_t)bid * 256 + t) * 8;
        float4 a = *reinterpret_cast<const float4*>(&x[i]);
        float4 b = *reinterpret_cast<const float4*>(&x[i + 4]);
        bf16x8 v;
        v[0]=f2bf(a.x); v[1]=f2bf(a.y); v[2]=f2bf(a.z); v[3]=f2bf(a.w);
        v[4]=f2bf(b.x); v[5]=f2bf(b.y); v[6]=f2bf(b.z); v[7]=f2bf(b.w);
        *reinterpret_cast<bf16x8*>(&xb[i]) = v;
        return;
    }
    const int tt = bid - 4096;
    const int w = tt >> 8;
    const int tl = tt & 255;
    const int bn = (tl & 15) * 64, bk = (tl >> 4) * 64;
    const float* W = (w==0)?Wq:(w==1)?Wk:(w==2)?Wv:Wo;
    short* out     = (w==0)?WqT:(w==1)?WkT:(w==2)?WvT:WoT;
    const int r = t >> 2, c0 = (t & 3) * 16;
    #pragma unroll
    for (int i = 0; i < 16; i += 4) {
        float4 v = *reinterpret_cast<const float4*>(&W[(size_t)(bk + r) * D_MODEL + bn + c0 + i]);
        tile[r][c0+i] = v.x; tile[r][c0+i+1] = v.y; tile[r][c0+i+2] = v.z; tile[r][c0+i+3] = v.w;
    }
    __syncthreads();
    bf16x8 H0, H1;
    #pragma unroll
    for (int i = 0; i < 8; i++) { H0[i] = f2bf(tile[c0 + i][r]); H1[i] = f2bf(tile[c0 + 8 + i][r]); }
    short* hp = &out[(size_t)(bn + r) * D_MODEL + bk + c0];
    *reinterpret_cast<bf16x8*>(hp) = H0;
    *reinterpret_cast<bf16x8*>(hp + 8) = H1;
}

// ---------------- fused QKV bf16 MFMA GEMM (R11 known-good: 3-deep, STAGE-early) ----------------
// K blocked: [bh][kt][region=dc*2+rh][lane][8]  holding K[kt*64+rh*32+(l&31)][dc*16+(l>>5)*8+j]
// V blocked: [bh][kt][region=kb*2+vh][lane][8]  holding V[kt*64+kb*16+(l>>5)*8+j][vh*32+(l&31)]
__global__ __launch_bounds__(256) void gemm_qkv(
    const short* __restrict__ A,
    const short* __restrict__ WqT, const short* __restrict__ WkT, const short* __restrict__ WvT,
    const float* __restrict__ bq, const float* __restrict__ bk, const float* __restrict__ bv,
    short* __restrict__ qo, short* __restrict__ ko, short* __restrict__ vo,
    const float qscale)
{
    __shared__ short As[3][128 * 32];
    __shared__ short Bs[3][128 * 32];
    const int tid = threadIdx.x, wave = tid >> 6, lane = tid & 63;
    const int g = lane >> 4, li = lane & 15;
    // T1: bijective XCD swizzle; grid 24x64 = 1536 = 8*192
    const int lin = blockIdx.x + blockIdx.y * 24;
    const int swz = (lin & 7) * 192 + (lin >> 3);
    const int bx = swz % 24, by = swz / 24;
    const int which = bx >> 3;
    const int bm = by * 128, bn = (bx & 7) * 128;
    const int wr = wave >> 1, wc = wave & 1;
    const int lrow = lane >> 2, lcol = (lane & 3) * 8;

    const short* BT = (which == 0) ? WqT : (which == 1) ? WkT : WvT;
    const float* bias = (which == 0) ? bq : (which == 1) ? bk : bv;
    short* out = (which == 0) ? qo : (which == 1) ? ko : vo;
    const float scale = (which == 0) ? qscale : 1.0f;

    f32x4 acc[4][4];
    #pragma unroll
    for (int i = 0; i < 4; i++)
        #pragma unroll
        for (int j = 0; j < 4; j++)
            #pragma unroll
            for (int r = 0; r < 4; r++) acc[i][j][r] = 0.f;

#define STAGEG(KS, BUF) do { \
        const int k0_ = (KS) * 32; \
        _Pragma("unroll") \
        for (int c = 0; c < 2; c++) { \
            const int ch = wave + c * 4; \
            const int row = ch * 16 + lrow; \
            GLD16(&A [(size_t)(bm + row) * D_MODEL + k0_ + lcol], &As[BUF][ch * 512]); \
            GLD16(&BT[(size_t)(bn + row) * D_MODEL + k0_ + lcol], &Bs[BUF][ch * 512]); \
        } \
    } while (0)

    STAGEG(0, 0);
    STAGEG(1, 1);

    const int NSTEP = D_MODEL / 32;
    for (int ks = 0; ks < NSTEP; ks++) {
        const int cur = ks % 3;
        if (ks + 2 < NSTEP) {
            STAGEG(ks + 2, (ks + 2) % 3);
            asm volatile("s_waitcnt vmcnt(8)" ::: "memory");
        } else if (ks + 1 < NSTEP) {
            asm volatile("s_waitcnt vmcnt(4)" ::: "memory");
        } else {
            asm volatile("s_waitcnt vmcnt(0)" ::: "memory");
        }
        __builtin_amdgcn_s_barrier();
        __builtin_amdgcn_sched_barrier(0);

        bf16x8 af[4], bfr[4];
        #pragma unroll
        for (int mi = 0; mi < 4; mi++) af[mi]  = *reinterpret_cast<const bf16x8*>(&As[cur][(wr * 64 + mi * 16 + li) * 32 + g * 8]);
        #pragma unroll
        for (int ni = 0; ni < 4; ni++) bfr[ni] = *reinterpret_cast<const bf16x8*>(&Bs[cur][(wc * 64 + ni * 16 + li) * 32 + g * 8]);
        #pragma unroll
        for (int mi = 0; mi < 4; mi++)
            #pragma unroll
            for (int ni = 0; ni < 4; ni++)
                acc[mi][ni] = MFMA16(af[mi], bfr[ni], acc[mi][ni]);
        __builtin_amdgcn_s_barrier();
    }
#undef STAGEG

    #pragma unroll
    for (int mi = 0; mi < 4; mi++) {
        #pragma unroll
        for (int r = 0; r < 4; r++) {
            const int m = bm + wr * 64 + mi * 16 + g * 4 + r;
            const int b = m >> 11, t = m & (SEQ - 1);
            #pragma unroll
            for (int ni = 0; ni < 4; ni++) {
                const int n = bn + wc * 64 + ni * 16 + li;
                const float val = (acc[mi][ni][r] + bias[n]) * scale;
                const int h = n >> 6, hd = n & 63;
                const int bh = b * NHEADS + h;
                const short sv = f2bf(val);
                if (which == 0) {
                    out[((size_t)bh * SEQ + t) * HD + hd] = sv;
                } else if (which == 1) {
                    const int kt = t >> 6, trow = t & 63;
                    const int rh = trow >> 5, rl = trow & 31;
                    const int dc = hd >> 4, hh = (hd >> 3) & 1, j = hd & 7;
                    out[((((size_t)bh * NKV + kt) * 8 + dc * 2 + rh) * 64 + hh * 32 + rl) * 8 + j] = sv;
                } else {
                    const int kt = t >> 6, trow = t & 63;
                    const int kb2 = trow >> 4, hh = (trow >> 3) & 1, j = trow & 7;
                    const int vh = hd >> 5, rl = hd & 31;
                    out[((((size_t)bh * NKV + kt) * 8 + kb2 * 2 + vh) * 64 + hh * 32 + rl) * 8 + j] = sv;
                }
            }
        }
    }
}

// ---------------- plain bf16 Wo GEMM (R8 known-good structure, unchanged) ----------------
__global__ __launch_bounds__(256) void gemm_wo(
    const short* __restrict__ A, const short* __restrict__ BT,
    const float* __restrict__ bias, float* __restrict__ out)
{
    __shared__ short As[3][128 * 32];
    __shared__ short Bs[3][128 * 32];
    const int tid = threadIdx.x, wave = tid >> 6, lane = tid & 63;
    const int g = lane >> 4, li = lane & 15;
    const int lin = blockIdx.x + blockIdx.y * 8;
    const int swz = (lin & 7) * 64 + (lin >> 3);
    const int bm = (swz >> 3) * 128, bn = (swz & 7) * 128;
    const int wr = wave >> 1, wc = wave & 1;
    const int lrow = lane >> 2, lcol = (lane & 3) * 8;

    f32x4 acc[4][4];
    #pragma unroll
    for (int i = 0; i < 4; i++)
        #pragma unroll
        for (int j = 0; j < 4; j++)
            #pragma unroll
            for (int r = 0; r < 4; r++) acc[i][j][r] = 0.f;

#define STAGEG(KS, BUF) do { \
        const int k0_ = (KS) * 32; \
        _Pragma("unroll") \
        for (int c = 0; c < 2; c++) { \
            const int ch = wave + c * 4; \
            const int row = ch * 16 + lrow; \
            GLD16(&A [(size_t)(bm + row) * D_MODEL + k0_ + lcol], &As[BUF][ch * 512]); \
            GLD16(&BT[(size_t)(bn + row) * D_MODEL + k0_ + lcol], &Bs[BUF][ch * 512]); \
        } \
    } while (0)

    STAGEG(0, 0);
    STAGEG(1, 1);

    const int NSTEP = D_MODEL / 32;
    for (int ks = 0; ks < NSTEP; ks++) {
        const int cur = ks % 3;
        if (ks + 2 < NSTEP) {
            STAGEG(ks + 2, (ks + 2) % 3);
            asm volatile("s_waitcnt vmcnt(8)" ::: "memory");
        } else if (ks + 1 < NSTEP) {
            asm volatile("s_waitcnt vmcnt(4)" ::: "memory");
        } else {
            asm volatile("s_waitcnt vmcnt(0)" ::: "memory");
        }
        __builtin_amdgcn_s_barrier();
        __builtin_amdgcn_sched_barrier(0);

        bf16x8 af[4], bfr[4];
        #pragma unroll
        for (int mi = 0; mi < 4; mi++) af[mi]  = *reinterpret_cast<const bf16x8*>(&As[cur][(wr * 64 + mi * 16 + li) * 32 + g * 8]);
        #pragma unroll
        for (int ni = 0; ni < 4; ni++) bfr[ni] = *reinterpret_cast<const bf16x8*>(&Bs[cur][(wc * 64 + ni * 16 + li) * 32 + g * 8]);
        #pragma unroll
        for (int mi = 0; mi < 4; mi++)
            #pragma unroll
            for (int ni = 0; ni < 4; ni++)
                acc[mi][ni] = MFMA16(af[mi], bfr[ni], acc[mi][ni]);
        __builtin_amdgcn_s_barrier();
    }
#undef STAGEG

    #pragma unroll
    for (int mi = 0; mi < 4; mi++) {
        #pragma unroll
        for (int r = 0; r < 4; r++) {
            const int m = bm + wr * 64 + mi * 16 + g * 4 + r;
            #pragma unroll
            for (int ni = 0; ni < 4; ni++) {
                const int n = bn + wc * 64 + ni * 16 + li;
                out[(size_t)m * D_MODEL + n] = acc[mi][ni][r] + bias[n];
            }
        }
    }
}

// ---------------- flash attention: SPLIT-KV (R17 body; grid z = kv-half) ----------------
// No online max -> partial states are exactly additive: each half writes
// unnormalized bf16 partial O + per-row l; merge_kv sums and normalizes.
// Grid 2048 blocks (5 resident/CU vs 4) and half the iterations per block.
__global__ __launch_bounds__(256) void attn_mfma(
    const short* __restrict__ q, const short* __restrict__ kblk,
    const short* __restrict__ vblk, short* __restrict__ pp_out,
    float* __restrict__ lp_out)
{
    __shared__ short Ks[2][64 * 64];
    __shared__ short Vs[2][64 * 64];

    const int bh = blockIdx.x;
    const int qt = blockIdx.y;
    const int half = blockIdx.z;
    const int tid = threadIdx.x;
    const int wave = tid >> 6, lane = tid & 63;
    const int ql = lane & 31;
    const int hi = lane >> 5;
    const int lb = lane * 8;   // shorts: lane*16B within a 1KB region

    const short* qp = q + ((size_t)bh * SEQ + qt * 128 + wave * 32 + ql) * HD;
    const bf16x8 qf0 = *reinterpret_cast<const bf16x8*>(qp + 0  + hi * 8);
    const bf16x8 qf1 = *reinterpret_cast<const bf16x8*>(qp + 16 + hi * 8);
    const bf16x8 qf2 = *reinterpret_cast<const bf16x8*>(qp + 32 + hi * 8);
    const bf16x8 qf3 = *reinterpret_cast<const bf16x8*>(qp + 48 + hi * 8);

    f32x16 o0, o1, Z;
    #pragma unroll
    for (int i = 0; i < 16; i++) { o0[i] = 0.f; o1[i] = 0.f; Z[i] = 0.f; }
    f32x2 dAcc; dAcc[0] = 0.f; dAcc[1] = 0.f;

    const int r0 = wave * 2, r1 = wave * 2 + 1;
    const int kt0 = half * NKV2;

#define STAGE(T, BUF) do { \
        const short* kg_ = kblk + ((size_t)(bh * NKV + (T)) * 8) * 512; \
        const short* vg_ = vblk + ((size_t)(bh * NKV + (T)) * 8) * 512; \
        GLD16(kg_ + r0 * 512 + lb, &Ks[BUF][r0 * 512]); \
        GLD16(kg_ + r1 * 512 + lb, &Ks[BUF][r1 * 512]); \
        GLD16(vg_ + r0 * 512 + lb, &Vs[BUF][r0 * 512]); \
        GLD16(vg_ + r1 * 512 + lb, &Vs[BUF][r1 * 512]); \
    } while (0)

    u32x4 pp[4];            // packed P(t-1), static indices only
    bf16x8 vr0[4], vr1[4];  // V(t-1) fragments in registers

    STAGE(kt0, 0);

    for (int it = 0; it < NKV2; it++) {
        const int cur = it & 1;
        asm volatile("s_waitcnt vmcnt(0)" ::: "memory");
        __builtin_amdgcn_s_barrier();
        __builtin_amdgcn_sched_barrier(0);
        if (it + 1 < NKV2) STAGE(kt0 + it + 1, cur ^ 1);

        const short* Kb = Ks[cur];
        const short* Vb = Vs[cur];

        // QK(t): S^T = K . Q^T, conflict-free region reads
        f32x16 s0, s1;
        __builtin_amdgcn_s_setprio(1);
#define QK_STEP(DC, QF, C0, C1) do { \
            const bf16x8 ka0 = *reinterpret_cast<const bf16x8*>(&Kb[((DC) * 2 + 0) * 512 + lb]); \
            const bf16x8 ka1 = *reinterpret_cast<const bf16x8*>(&Kb[((DC) * 2 + 1) * 512 + lb]); \
            s0 = MFMA32(ka0, QF, C0); \
            s1 = MFMA32(ka1, QF, C1); \
        } while (0)
        QK_STEP(0, qf0, Z, Z);
        QK_STEP(1, qf1, s0, s1);
        QK_STEP(2, qf2, s0, s1);
        QK_STEP(3, qf3, s0, s1);
#undef QK_STEP

        // PV(t-1): pure register MFMAs
        if (it > 0) {
            #pragma unroll
            for (int KB = 0; KB < 4; KB++) {
                const bf16x8 pf = __builtin_bit_cast(bf16x8, pp[KB]);
                o0 = MFMA32(vr0[KB], pf, o0);
                o1 = MFMA32(vr1[KB], pf, o1);
            }
        }
        // reload V(t) into regs (consumed next iter)
        #pragma unroll
        for (int KB = 0; KB < 4; KB++) {
            vr0[KB] = *reinterpret_cast<const bf16x8*>(&Vb[(KB * 2 + 0) * 512 + lb]);
            vr1[KB] = *reinterpret_cast<const bf16x8*>(&Vb[(KB * 2 + 1) * 512 + lb]);
        }
        __builtin_amdgcn_s_setprio(0);

        // p = 2^S
        #pragma unroll
        for (int i = 0; i < 16; i++) s0[i] = fexp2(s0[i]);
        #pragma unroll
        for (int i = 0; i < 16; i++) s1[i] = fexp2(s1[i]);

        // deferred denominator: pairwise tree -> dAcc
        {
            f32x2 p0 = pkadd(SH2(s0, 0), SH2(s0, 2));
            f32x2 p1 = pkadd(SH2(s0, 4), SH2(s0, 6));
            f32x2 p2 = pkadd(SH2(s0, 8), SH2(s0, 10));
            f32x2 p3 = pkadd(SH2(s0, 12), SH2(s0, 14));
            f32x2 p4 = pkadd(SH2(s1, 0), SH2(s1, 2));
            f32x2 p5 = pkadd(SH2(s1, 4), SH2(s1, 6));
            f32x2 p6 = pkadd(SH2(s1, 8), SH2(s1, 10));
            f32x2 p7 = pkadd(SH2(s1, 12), SH2(s1, 14));
            p0 = pkadd(p0, p1); p2 = pkadd(p2, p3);
            p4 = pkadd(p4, p5); p6 = pkadd(p6, p7);
            p0 = pkadd(p0, p2); p4 = pkadd(p4, p6);
            p0 = pkadd(p0, p4);
            dAcc = pkadd(dAcc, p0);
        }

        // pack P(t) for next iter's PV
#define PACK(KB, SS, B) do { \
            const unsigned a0 = cvtpk(SS[(B) + 0], SS[(B) + 1]); \
            const unsigned a1 = cvtpk(SS[(B) + 2], SS[(B) + 3]); \
            const unsigned a2 = cvtpk(SS[(B) + 4], SS[(B) + 5]); \
            const unsigned a3 = cvtpk(SS[(B) + 6], SS[(B) + 7]); \
            const u32x2 r02 = __builtin_amdgcn_permlane32_swap(a0, a2, false, false); \
            const u32x2 r13 = __builtin_amdgcn_permlane32_swap(a1, a3, false, false); \
            pp[KB][0] = r02[0]; pp[KB][1] = r13[0]; pp[KB][2] = r02[1]; pp[KB][3] = r13[1]; \
        } while (0)
        PACK(0, s0, 0); PACK(1, s0, 8); PACK(2, s1, 0); PACK(3, s1, 8);
#undef PACK

        // retire this wave's LDS reads before it can reach the next barrier
        asm volatile("s_waitcnt lgkmcnt(0)" ::: "memory");
        __builtin_amdgcn_sched_barrier(0);
    }
#undef STAGE

    // epilogue: final PV
    #pragma unroll
    for (int KB = 0; KB < 4; KB++) {
        const bf16x8 pf = __builtin_bit_cast(bf16x8, pp[KB]);
        o0 = MFMA32(vr0[KB], pf, o0);
        o1 = MFMA32(vr1[KB], pf, o1);
    }

    // partial denominator for this half (both partner lanes get full half-sum)
    float lR = dAcc[0] + dAcc[1];
    lR += __shfl_xor(lR, 32);

    // write UNNORMALIZED partial O (bf16) + l to workspace
    const int t = qt * 128 + wave * 32 + ql;
    const size_t row = (size_t)bh * SEQ + t;
    const size_t pbase = ((size_t)half * BHROWS + row) * HD;
    #pragma unroll
    for (int blk = 0; blk < 4; blk++) {
        uint2 w0, w1;
        w0.x = cvtpk(o0[4*blk + 0], o0[4*blk + 1]);
        w0.y = cvtpk(o0[4*blk + 2], o0[4*blk + 3]);
        w1.x = cvtpk(o1[4*blk + 0], o1[4*blk + 1]);
        w1.y = cvtpk(o1[4*blk + 2], o1[4*blk + 3]);
        *reinterpret_cast<uint2*>(&pp_out[pbase + 8*blk + 4*hi])      = w0;
        *reinterpret_cast<uint2*>(&pp_out[pbase + 32 + 8*blk + 4*hi]) = w1;
    }
    if (hi == 0) lp_out[(size_t)half * BHROWS + row] = lR;
}

// ---------------- merge: ctx = (P0 + P1) / (l0 + l1), ctx layout [B,T,D] ----------------
__global__ __launch_bounds__(256) void merge_kv(
    const short* __restrict__ pp, const float* __restrict__ lp, short* __restrict__ ch)
{
    const int idx = blockIdx.x * 256 + threadIdx.x;
    const int row = idx >> 3;             // bh*SEQ + t  (0..BHROWS-1)
    const int dg  = (idx & 7) * 8;
    const size_t S1h = (size_t)BHROWS * HD;
    const u32x4 a = *reinterpret_cast<const u32x4*>(&pp[(size_t)row * HD + dg]);
    const u32x4 c = *reinterpret_cast<const u32x4*>(&pp[S1h + (size_t)row * HD + dg]);
    const float inv = 1.0f / (lp[row] + lp[BHROWS + row]);
    u32x4 o;
    #pragma unroll
    for (int i = 0; i < 4; i++) {
        const float a0 = bf2f((short)(a[i] & 0xFFFF)), a1 = bf2f((short)(a[i] >> 16));
        const float c0 = bf2f((short)(c[i] & 0xFFFF)), c1 = bf2f((short)(c[i] >> 16));
        o[i] = cvtpk((a0 + c0) * inv, (a1 + c1) * inv);
    }
    const int bh = row >> 11, t = row & (SEQ - 1);
    const int b = bh >> 4, h = bh & (NHEADS - 1);
    *reinterpret_cast<u32x4*>(&ch[((size_t)(b * SEQ + t)) * D_MODEL + h * HD + dg]) = o;
}

extern "C" void kernel_launch(void* const* d_in, const int* in_sizes, int n_in,
                              void* d_out, int out_size, void* d_ws, size_t ws_size,
                              hipStream_t stream) {
    const float* x  = (const float*)d_in[0];
    const float* Wq = (const float*)d_in[1];
    const float* bq = (const float*)d_in[2];
    const float* Wk = (const float*)d_in[3];
    const float* bk = (const float*)d_in[4];
    const float* Wv = (const float*)d_in[5];
    const float* bv = (const float*)d_in[6];
    const float* Wo = (const float*)d_in[7];
    const float* bo = (const float*)d_in[8];

    const size_t S1 = (size_t)MROWS * D_MODEL;   // 8388608 elems
    const size_t SW = (size_t)D_MODEL * D_MODEL;
    short* xb  = (short*)d_ws;
    short* qb  = xb + S1;
    short* kb  = qb + S1;            // K blocked [bh][kt][8 regions][64][8]
    short* vb  = kb + S1;            // V blocked
    short* chb = vb + S1;            // ctx bf16 [B,T,D]
    short* WqT = chb + S1;
    short* WkT = WqT + SW;
    short* WvT = WkT + SW;
    short* WoT = WvT + SW;
    short* ppb = WoT + SW;           // partial O: [2][BHROWS][HD] bf16 = 33.5 MB
    float* lpb = (float*)(ppb + 2 * S1);   // partial l: [2][BHROWS] f32 = 1 MB
    // total ws: ~127 MB

    prep<<<5120, 256, 0, stream>>>(x, Wq, Wk, Wv, Wo, xb, WqT, WkT, WvT, WoT);

    // Q pre-scaled by 1/sqrt(HD) * log2(e): QK^T output lands in exp2 domain.
    const float QSCALE = 0.125f * 1.4426950408889634f;
    gemm_qkv<<<dim3(24, 64), 256, 0, stream>>>(xb, WqT, WkT, WvT, bq, bk, bv,
                                               qb, kb, vb, QSCALE);
    attn_mfma<<<dim3(BATCH * NHEADS, SEQ / 128, 2), 256, 0, stream>>>(qb, kb, vb, ppb, lpb);
    merge_kv<<<dim3(BHROWS * 8 / 256), 256, 0, stream>>>(ppb, lpb, chb);
    gemm_wo<<<dim3(8, 64), 256, 0, stream>>>(chb, WoT, bo, (float*)d_out);
}

// Round 19
// 196.039 us; speedup vs baseline: 1.0772x; 1.0772x over previous
//
#include <hip/hip_runtime.h>
#include <hip/hip_bf16.h>

#define D_MODEL 1024
#define NHEADS  16
#define HD      64
#define BATCH   4
#define SEQ     2048
#define MROWS   (BATCH*SEQ)   // 8192
#define NKV     (SEQ/64)      // 32 kv-tiles per bh

typedef __attribute__((ext_vector_type(8))) short bf16x8;
typedef __attribute__((ext_vector_type(4))) float f32x4;
typedef __attribute__((ext_vector_type(16))) float f32x16;
typedef __attribute__((ext_vector_type(2))) float f32x2;
typedef __attribute__((ext_vector_type(4))) unsigned int u32x4;
typedef __attribute__((ext_vector_type(2))) unsigned int u32x2;
#define MFMA16(a,b,c) __builtin_amdgcn_mfma_f32_16x16x32_bf16(a,b,c,0,0,0)
#define MFMA32(a,b,c) __builtin_amdgcn_mfma_f32_32x32x16_bf16(a,b,c,0,0,0)

__device__ __forceinline__ short f2bf(float f) {
    __hip_bfloat16 h = __float2bfloat16(f);   // RNE
    return *reinterpret_cast<short*>(&h);
}
// single-instruction packed f32x2 -> bf16x2 (T12; RNE)
__device__ __forceinline__ unsigned cvtpk(float a, float b) {
    unsigned r; asm("v_cvt_pk_bf16_f32 %0, %1, %2" : "=v"(r) : "v"(a), "v"(b)); return r;
}
// raw 2^x (v_exp_f32 is natively exp2)
__device__ __forceinline__ float fexp2(float x) {
    float r; asm("v_exp_f32 %0, %1" : "=v"(r) : "v"(x)); return r;
}
// full-rate packed fp32 add (CDNA dual-f32 pipe)
__device__ __forceinline__ f32x2 pkadd(f32x2 a, f32x2 b) {
    f32x2 d; asm("v_pk_add_f32 %0, %1, %2" : "=v"(d) : "v"(a), "v"(b)); return d;
}
#define SH2(V,I) __builtin_shufflevector(V, V, I, (I)+1)

typedef const __attribute__((address_space(1))) unsigned char* gas_t;
typedef __attribute__((address_space(3))) unsigned char* las_t;
#define GLD16(gp, lp) __builtin_amdgcn_global_load_lds((gas_t)(gp), (las_t)(lp), 16, 0, 0)

// ---------------- fused prep: round x to bf16 + 4x W transpose ----------------
__global__ __launch_bounds__(256) void prep(
    const float* __restrict__ x,
    const float* __restrict__ Wq, const float* __restrict__ Wk,
    const float* __restrict__ Wv, const float* __restrict__ Wo,
    short* __restrict__ xb,
    short* __restrict__ WqT, short* __restrict__ WkT,
    short* __restrict__ WvT, short* __restrict__ WoT)
{
    __shared__ float tile[64][65];
    const int bid = blockIdx.x;
    const int t = threadIdx.x;
    if (bid < 4096) {
        const size_t i = ((size_t)bid * 256 + t) * 8;
        float4 a = *reinterpret_cast<const float4*>(&x[i]);
        float4 b = *reinterpret_cast<const float4*>(&x[i + 4]);
        bf16x8 v;
        v[0]=f2bf(a.x); v[1]=f2bf(a.y); v[2]=f2bf(a.z); v[3]=f2bf(a.w);
        v[4]=f2bf(b.x); v[5]=f2bf(b.y); v[6]=f2bf(b.z); v[7]=f2bf(b.w);
        *reinterpret_cast<bf16x8*>(&xb[i]) = v;
        return;
    }
    const int tt = bid - 4096;
    const int w = tt >> 8;
    const int tl = tt & 255;
    const int bn = (tl & 15) * 64, bk = (tl >> 4) * 64;
    const float* W = (w==0)?Wq:(w==1)?Wk:(w==2)?Wv:Wo;
    short* out     = (w==0)?WqT:(w==1)?WkT:(w==2)?WvT:WoT;
    const int r = t >> 2, c0 = (t & 3) * 16;
    #pragma unroll
    for (int i = 0; i < 16; i += 4) {
        float4 v = *reinterpret_cast<const float4*>(&W[(size_t)(bk + r) * D_MODEL + bn + c0 + i]);
        tile[r][c0+i] = v.x; tile[r][c0+i+1] = v.y; tile[r][c0+i+2] = v.z; tile[r][c0+i+3] = v.w;
    }
    __syncthreads();
    bf16x8 H0, H1;
    #pragma unroll
    for (int i = 0; i < 8; i++) { H0[i] = f2bf(tile[c0 + i][r]); H1[i] = f2bf(tile[c0 + 8 + i][r]); }
    short* hp = &out[(size_t)(bn + r) * D_MODEL + bk + c0];
    *reinterpret_cast<bf16x8*>(hp) = H0;
    *reinterpret_cast<bf16x8*>(hp + 8) = H1;
}

// ---------------- fused QKV bf16 MFMA GEMM (R11 known-good: 3-deep, STAGE-early) ----------------
// K blocked: [bh][kt][region=dc*2+rh][lane][8]  holding K[kt*64+rh*32+(l&31)][dc*16+(l>>5)*8+j]
// V blocked: [bh][kt][region=kb*2+vh][lane][8]  holding V[kt*64+kb*16+(l>>5)*8+j][vh*32+(l&31)]
__global__ __launch_bounds__(256) void gemm_qkv(
    const short* __restrict__ A,
    const short* __restrict__ WqT, const short* __restrict__ WkT, const short* __restrict__ WvT,
    const float* __restrict__ bq, const float* __restrict__ bk, const float* __restrict__ bv,
    short* __restrict__ qo, short* __restrict__ ko, short* __restrict__ vo,
    const float qscale)
{
    __shared__ short As[3][128 * 32];
    __shared__ short Bs[3][128 * 32];
    const int tid = threadIdx.x, wave = tid >> 6, lane = tid & 63;
    const int g = lane >> 4, li = lane & 15;
    // T1: bijective XCD swizzle; grid 24x64 = 1536 = 8*192
    const int lin = blockIdx.x + blockIdx.y * 24;
    const int swz = (lin & 7) * 192 + (lin >> 3);
    const int bx = swz % 24, by = swz / 24;
    const int which = bx >> 3;
    const int bm = by * 128, bn = (bx & 7) * 128;
    const int wr = wave >> 1, wc = wave & 1;
    const int lrow = lane >> 2, lcol = (lane & 3) * 8;

    const short* BT = (which == 0) ? WqT : (which == 1) ? WkT : WvT;
    const float* bias = (which == 0) ? bq : (which == 1) ? bk : bv;
    short* out = (which == 0) ? qo : (which == 1) ? ko : vo;
    const float scale = (which == 0) ? qscale : 1.0f;

    f32x4 acc[4][4];
    #pragma unroll
    for (int i = 0; i < 4; i++)
        #pragma unroll
        for (int j = 0; j < 4; j++)
            #pragma unroll
            for (int r = 0; r < 4; r++) acc[i][j][r] = 0.f;

#define STAGEG(KS, BUF) do { \
        const int k0_ = (KS) * 32; \
        _Pragma("unroll") \
        for (int c = 0; c < 2; c++) { \
            const int ch = wave + c * 4; \
            const int row = ch * 16 + lrow; \
            GLD16(&A [(size_t)(bm + row) * D_MODEL + k0_ + lcol], &As[BUF][ch * 512]); \
            GLD16(&BT[(size_t)(bn + row) * D_MODEL + k0_ + lcol], &Bs[BUF][ch * 512]); \
        } \
    } while (0)

    STAGEG(0, 0);
    STAGEG(1, 1);

    const int NSTEP = D_MODEL / 32;
    for (int ks = 0; ks < NSTEP; ks++) {
        const int cur = ks % 3;
        if (ks + 2 < NSTEP) {
            STAGEG(ks + 2, (ks + 2) % 3);
            asm volatile("s_waitcnt vmcnt(8)" ::: "memory");
        } else if (ks + 1 < NSTEP) {
            asm volatile("s_waitcnt vmcnt(4)" ::: "memory");
        } else {
            asm volatile("s_waitcnt vmcnt(0)" ::: "memory");
        }
        __builtin_amdgcn_s_barrier();
        __builtin_amdgcn_sched_barrier(0);

        bf16x8 af[4], bfr[4];
        #pragma unroll
        for (int mi = 0; mi < 4; mi++) af[mi]  = *reinterpret_cast<const bf16x8*>(&As[cur][(wr * 64 + mi * 16 + li) * 32 + g * 8]);
        #pragma unroll
        for (int ni = 0; ni < 4; ni++) bfr[ni] = *reinterpret_cast<const bf16x8*>(&Bs[cur][(wc * 64 + ni * 16 + li) * 32 + g * 8]);
        #pragma unroll
        for (int mi = 0; mi < 4; mi++)
            #pragma unroll
            for (int ni = 0; ni < 4; ni++)
                acc[mi][ni] = MFMA16(af[mi], bfr[ni], acc[mi][ni]);
        __builtin_amdgcn_s_barrier();
    }
#undef STAGEG

    #pragma unroll
    for (int mi = 0; mi < 4; mi++) {
        #pragma unroll
        for (int r = 0; r < 4; r++) {
            const int m = bm + wr * 64 + mi * 16 + g * 4 + r;
            const int b = m >> 11, t = m & (SEQ - 1);
            #pragma unroll
            for (int ni = 0; ni < 4; ni++) {
                const int n = bn + wc * 64 + ni * 16 + li;
                const float val = (acc[mi][ni][r] + bias[n]) * scale;
                const int h = n >> 6, hd = n & 63;
                const int bh = b * NHEADS + h;
                const short sv = f2bf(val);
                if (which == 0) {
                    out[((size_t)bh * SEQ + t) * HD + hd] = sv;
                } else if (which == 1) {
                    const int kt = t >> 6, trow = t & 63;
                    const int rh = trow >> 5, rl = trow & 31;
                    const int dc = hd >> 4, hh = (hd >> 3) & 1, j = hd & 7;
                    out[((((size_t)bh * NKV + kt) * 8 + dc * 2 + rh) * 64 + hh * 32 + rl) * 8 + j] = sv;
                } else {
                    const int kt = t >> 6, trow = t & 63;
                    const int kb2 = trow >> 4, hh = (trow >> 3) & 1, j = trow & 7;
                    const int vh = hd >> 5, rl = hd & 31;
                    out[((((size_t)bh * NKV + kt) * 8 + kb2 * 2 + vh) * 64 + hh * 32 + rl) * 8 + j] = sv;
                }
            }
        }
    }
}

// ---------------- plain bf16 Wo GEMM (R8 known-good structure, unchanged) ----------------
__global__ __launch_bounds__(256) void gemm_wo(
    const short* __restrict__ A, const short* __restrict__ BT,
    const float* __restrict__ bias, float* __restrict__ out)
{
    __shared__ short As[3][128 * 32];
    __shared__ short Bs[3][128 * 32];
    const int tid = threadIdx.x, wave = tid >> 6, lane = tid & 63;
    const int g = lane >> 4, li = lane & 15;
    const int lin = blockIdx.x + blockIdx.y * 8;
    const int swz = (lin & 7) * 64 + (lin >> 3);
    const int bm = (swz >> 3) * 128, bn = (swz & 7) * 128;
    const int wr = wave >> 1, wc = wave & 1;
    const int lrow = lane >> 2, lcol = (lane & 3) * 8;

    f32x4 acc[4][4];
    #pragma unroll
    for (int i = 0; i < 4; i++)
        #pragma unroll
        for (int j = 0; j < 4; j++)
            #pragma unroll
            for (int r = 0; r < 4; r++) acc[i][j][r] = 0.f;

#define STAGEG(KS, BUF) do { \
        const int k0_ = (KS) * 32; \
        _Pragma("unroll") \
        for (int c = 0; c < 2; c++) { \
            const int ch = wave + c * 4; \
            const int row = ch * 16 + lrow; \
            GLD16(&A [(size_t)(bm + row) * D_MODEL + k0_ + lcol], &As[BUF][ch * 512]); \
            GLD16(&BT[(size_t)(bn + row) * D_MODEL + k0_ + lcol], &Bs[BUF][ch * 512]); \
        } \
    } while (0)

    STAGEG(0, 0);
    STAGEG(1, 1);

    const int NSTEP = D_MODEL / 32;
    for (int ks = 0; ks < NSTEP; ks++) {
        const int cur = ks % 3;
        if (ks + 2 < NSTEP) {
            STAGEG(ks + 2, (ks + 2) % 3);
            asm volatile("s_waitcnt vmcnt(8)" ::: "memory");
        } else if (ks + 1 < NSTEP) {
            asm volatile("s_waitcnt vmcnt(4)" ::: "memory");
        } else {
            asm volatile("s_waitcnt vmcnt(0)" ::: "memory");
        }
        __builtin_amdgcn_s_barrier();
        __builtin_amdgcn_sched_barrier(0);

        bf16x8 af[4], bfr[4];
        #pragma unroll
        for (int mi = 0; mi < 4; mi++) af[mi]  = *reinterpret_cast<const bf16x8*>(&As[cur][(wr * 64 + mi * 16 + li) * 32 + g * 8]);
        #pragma unroll
        for (int ni = 0; ni < 4; ni++) bfr[ni] = *reinterpret_cast<const bf16x8*>(&Bs[cur][(wc * 64 + ni * 16 + li) * 32 + g * 8]);
        #pragma unroll
        for (int mi = 0; mi < 4; mi++)
            #pragma unroll
            for (int ni = 0; ni < 4; ni++)
                acc[mi][ni] = MFMA16(af[mi], bfr[ni], acc[mi][ni]);
        __builtin_amdgcn_s_barrier();
    }
#undef STAGEG

    #pragma unroll
    for (int mi = 0; mi < 4; mi++) {
        #pragma unroll
        for (int r = 0; r < 4; r++) {
            const int m = bm + wr * 64 + mi * 16 + g * 4 + r;
            #pragma unroll
            for (int ni = 0; ni < 4; ni++) {
                const int n = bn + wc * 64 + ni * 16 + li;
                out[(size_t)m * D_MODEL + n] = acc[mi][ni][r] + bias[n];
            }
        }
    }
}

// ---------------- flash attention (R17: single barrier per iteration) ----------------
// [vmcnt(0) -> s_barrier -> STAGE(kt+1) -> body -> lgkmcnt(0)] per iter.
// STAGE(kt+1) writes buf cur^1, last read in iter kt-1; every wave's reads
// retired (lgkmcnt(0)) before crossing barrier(kt) -> post-barrier write safe.
__global__ __launch_bounds__(256) void attn_mfma(
    const short* __restrict__ q, const short* __restrict__ kblk,
    const short* __restrict__ vblk, short* __restrict__ ch)
{
    __shared__ short Ks[2][64 * 64];
    __shared__ short Vs[2][64 * 64];

    const int bh = blockIdx.x;
    const int b  = bh >> 4, h = bh & (NHEADS - 1);
    const int qt = blockIdx.y;
    const int tid = threadIdx.x;
    const int wave = tid >> 6, lane = tid & 63;
    const int ql = lane & 31;
    const int hi = lane >> 5;
    const int lb = lane * 8;   // shorts: lane*16B within a 1KB region

    const short* qp = q + ((size_t)bh * SEQ + qt * 128 + wave * 32 + ql) * HD;
    const bf16x8 qf0 = *reinterpret_cast<const bf16x8*>(qp + 0  + hi * 8);
    const bf16x8 qf1 = *reinterpret_cast<const bf16x8*>(qp + 16 + hi * 8);
    const bf16x8 qf2 = *reinterpret_cast<const bf16x8*>(qp + 32 + hi * 8);
    const bf16x8 qf3 = *reinterpret_cast<const bf16x8*>(qp + 48 + hi * 8);

    f32x16 o0, o1, Z;
    #pragma unroll
    for (int i = 0; i < 16; i++) { o0[i] = 0.f; o1[i] = 0.f; Z[i] = 0.f; }
    f32x2 dAcc; dAcc[0] = 0.f; dAcc[1] = 0.f;

    const int r0 = wave * 2, r1 = wave * 2 + 1;

#define STAGE(T, BUF) do { \
        const short* kg_ = kblk + ((size_t)(bh * NKV + (T)) * 8) * 512; \
        const short* vg_ = vblk + ((size_t)(bh * NKV + (T)) * 8) * 512; \
        GLD16(kg_ + r0 * 512 + lb, &Ks[BUF][r0 * 512]); \
        GLD16(kg_ + r1 * 512 + lb, &Ks[BUF][r1 * 512]); \
        GLD16(vg_ + r0 * 512 + lb, &Vs[BUF][r0 * 512]); \
        GLD16(vg_ + r1 * 512 + lb, &Vs[BUF][r1 * 512]); \
    } while (0)

    u32x4 pp[4];            // packed P(t-1), static indices only
    bf16x8 vr0[4], vr1[4];  // V(t-1) fragments in registers

    STAGE(0, 0);

    const int NT = NKV;
    for (int kt = 0; kt < NT; kt++) {
        const int cur = kt & 1;
        // tile kt's loads were issued a full iteration ago -> near-zero wait
        asm volatile("s_waitcnt vmcnt(0)" ::: "memory");
        __builtin_amdgcn_s_barrier();
        __builtin_amdgcn_sched_barrier(0);
        // safe post-barrier: buf cur^1 was last read in iter kt-1, all retired
        if (kt + 1 < NT) STAGE(kt + 1, cur ^ 1);

        const short* Kb = Ks[cur];
        const short* Vb = Vs[cur];

        // QK(t): S^T = K . Q^T, conflict-free region reads
        f32x16 s0, s1;
        __builtin_amdgcn_s_setprio(1);
#define QK_STEP(DC, QF, C0, C1) do { \
            const bf16x8 ka0 = *reinterpret_cast<const bf16x8*>(&Kb[((DC) * 2 + 0) * 512 + lb]); \
            const bf16x8 ka1 = *reinterpret_cast<const bf16x8*>(&Kb[((DC) * 2 + 1) * 512 + lb]); \
            s0 = MFMA32(ka0, QF, C0); \
            s1 = MFMA32(ka1, QF, C1); \
        } while (0)
        QK_STEP(0, qf0, Z, Z);
        QK_STEP(1, qf1, s0, s1);
        QK_STEP(2, qf2, s0, s1);
        QK_STEP(3, qf3, s0, s1);
#undef QK_STEP

        // PV(t-1): pure register MFMAs
        if (kt > 0) {
            #pragma unroll
            for (int KB = 0; KB < 4; KB++) {
                const bf16x8 pf = __builtin_bit_cast(bf16x8, pp[KB]);
                o0 = MFMA32(vr0[KB], pf, o0);
                o1 = MFMA32(vr1[KB], pf, o1);
            }
        }
        // reload V(t) into regs (consumed next iter)
        #pragma unroll
        for (int KB = 0; KB < 4; KB++) {
            vr0[KB] = *reinterpret_cast<const bf16x8*>(&Vb[(KB * 2 + 0) * 512 + lb]);
            vr1[KB] = *reinterpret_cast<const bf16x8*>(&Vb[(KB * 2 + 1) * 512 + lb]);
        }
        __builtin_amdgcn_s_setprio(0);

        // p = 2^S
        #pragma unroll
        for (int i = 0; i < 16; i++) s0[i] = fexp2(s0[i]);
        #pragma unroll
        for (int i = 0; i < 16; i++) s1[i] = fexp2(s1[i]);

        // deferred denominator: pairwise tree -> dAcc (no cross-lane work here)
        {
            f32x2 p0 = pkadd(SH2(s0, 0), SH2(s0, 2));
            f32x2 p1 = pkadd(SH2(s0, 4), SH2(s0, 6));
            f32x2 p2 = pkadd(SH2(s0, 8), SH2(s0, 10));
            f32x2 p3 = pkadd(SH2(s0, 12), SH2(s0, 14));
            f32x2 p4 = pkadd(SH2(s1, 0), SH2(s1, 2));
            f32x2 p5 = pkadd(SH2(s1, 4), SH2(s1, 6));
            f32x2 p6 = pkadd(SH2(s1, 8), SH2(s1, 10));
            f32x2 p7 = pkadd(SH2(s1, 12), SH2(s1, 14));
            p0 = pkadd(p0, p1); p2 = pkadd(p2, p3);
            p4 = pkadd(p4, p5); p6 = pkadd(p6, p7);
            p0 = pkadd(p0, p2); p4 = pkadd(p4, p6);
            p0 = pkadd(p0, p4);
            dAcc = pkadd(dAcc, p0);
        }

        // pack P(t) for next iter's PV
#define PACK(KB, SS, B) do { \
            const unsigned a0 = cvtpk(SS[(B) + 0], SS[(B) + 1]); \
            const unsigned a1 = cvtpk(SS[(B) + 2], SS[(B) + 3]); \
            const unsigned a2 = cvtpk(SS[(B) + 4], SS[(B) + 5]); \
            const unsigned a3 = cvtpk(SS[(B) + 6], SS[(B) + 7]); \
            const u32x2 r02 = __builtin_amdgcn_permlane32_swap(a0, a2, false, false); \
            const u32x2 r13 = __builtin_amdgcn_permlane32_swap(a1, a3, false, false); \
            pp[KB][0] = r02[0]; pp[KB][1] = r13[0]; pp[KB][2] = r02[1]; pp[KB][3] = r13[1]; \
        } while (0)
        PACK(0, s0, 0); PACK(1, s0, 8); PACK(2, s1, 0); PACK(3, s1, 8);
#undef PACK

        // retire this wave's LDS reads before it can reach the next barrier
        asm volatile("s_waitcnt lgkmcnt(0)" ::: "memory");
        __builtin_amdgcn_sched_barrier(0);
    }
#undef STAGE

    // epilogue: final PV(NT-1)
    #pragma unroll
    for (int KB = 0; KB < 4; KB++) {
        const bf16x8 pf = __builtin_bit_cast(bf16x8, pp[KB]);
        o0 = MFMA32(vr0[KB], pf, o0);
        o1 = MFMA32(vr1[KB], pf, o1);
    }

    // final denominator reduce (once): lane-local sum + partner half
    float lR = dAcc[0] + dAcc[1];
    lR += __shfl_xor(lR, 32);

    // O^T C-layout -> ctx [B,T,D] bf16, 8B vector stores
    const float inv = 1.0f / lR;
    const int t = qt * 128 + wave * 32 + ql;
    const size_t base = ((size_t)(b * SEQ + t)) * D_MODEL + h * HD;
    #pragma unroll
    for (int blk = 0; blk < 4; blk++) {
        uint2 w0, w1;
        w0.x = cvtpk(o0[4*blk + 0] * inv, o0[4*blk + 1] * inv);
        w0.y = cvtpk(o0[4*blk + 2] * inv, o0[4*blk + 3] * inv);
        w1.x = cvtpk(o1[4*blk + 0] * inv, o1[4*blk + 1] * inv);
        w1.y = cvtpk(o1[4*blk + 2] * inv, o1[4*blk + 3] * inv);
        *reinterpret_cast<uint2*>(&ch[base + 8*blk + 4*hi])      = w0;
        *reinterpret_cast<uint2*>(&ch[base + 32 + 8*blk + 4*hi]) = w1;
    }
}

extern "C" void kernel_launch(void* const* d_in, const int* in_sizes, int n_in,
                              void* d_out, int out_size, void* d_ws, size_t ws_size,
                              hipStream_t stream) {
    const float* x  = (const float*)d_in[0];
    const float* Wq = (const float*)d_in[1];
    const float* bq = (const float*)d_in[2];
    const float* Wk = (const float*)d_in[3];
    const float* bk = (const float*)d_in[4];
    const float* Wv = (const float*)d_in[5];
    const float* bv = (const float*)d_in[6];
    const float* Wo = (const float*)d_in[7];
    const float* bo = (const float*)d_in[8];

    const size_t S1 = (size_t)MROWS * D_MODEL;
    const size_t SW = (size_t)D_MODEL * D_MODEL;
    short* xb  = (short*)d_ws;
    short* qb  = xb + S1;
    short* kb  = qb + S1;            // K blocked [bh][kt][8 regions][64][8]
    short* vb  = kb + S1;            // V blocked
    short* chb = vb + S1;            // ctx bf16 [B,T,D]
    short* WqT = chb + S1;
    short* WkT = WqT + SW;
    short* WvT = WkT + SW;
    short* WoT = WvT + SW;

    prep<<<5120, 256, 0, stream>>>(x, Wq, Wk, Wv, Wo, xb, WqT, WkT, WvT, WoT);

    // Q pre-scaled by 1/sqrt(HD) * log2(e): QK^T output lands in exp2 domain.
    const float QSCALE = 0.125f * 1.4426950408889634f;
    gemm_qkv<<<dim3(24, 64), 256, 0, stream>>>(xb, WqT, WkT, WvT, bq, bk, bv,
                                               qb, kb, vb, QSCALE);
    attn_mfma<<<dim3(BATCH * NHEADS, SEQ / 128), 256, 0, stream>>>(qb, kb, vb, chb);
    gemm_wo<<<dim3(8, 64), 256, 0, stream>>>(chb, WoT, bo, (float*)d_out);
}